// Round 6
// baseline (123.383 us; speedup 1.0000x reference)
//
#include <hip/hip_runtime.h>
#include <math.h>

#define DIM 256
#define BATCH 16
#define NO 64
#define NI 512
#define NEG_SLOPE 0.01f
#define CSCALE 2.885390081777927f   // 2*log2(e): tanh(x) = 1 - 2/(exp2(CSCALE*x)+1)
#define OT 4                        // o's per attn block (1 block/CU, 1024 thr)

typedef float f32x4 __attribute__((ext_vector_type(4)));
typedef __bf16 bf16x8 __attribute__((ext_vector_type(8)));
typedef unsigned int u32x4 __attribute__((ext_vector_type(4)));

// ---------------------------------------------------------------------------
// split f32 -> bf16 hi (RNE, returned as low-16 bits) + exact f32 residual
// ---------------------------------------------------------------------------
__device__ __forceinline__ void split2(float f, unsigned int& hi16, float& lo) {
  unsigned int u = __builtin_bit_cast(unsigned int, f);
  unsigned int h = (u + 0x7FFFu + ((u >> 16) & 1u)) & 0xFFFF0000u; // RNE bf16, as f32 bits
  hi16 = h >> 16;
  lo = f - __builtin_bit_cast(float, h);   // exact (Sterbenz)
}
__device__ __forceinline__ unsigned int rne16(float f) {
  unsigned int u = __builtin_bit_cast(unsigned int, f);
  return (u + 0x7FFFu + ((u >> 16) & 1u)) >> 16;
}

struct __align__(8) U2 { unsigned int x, y; };

// ---------------------------------------------------------------------------
// Kernel 1 (blocks 0..575): GEMM  out[r,h] = sum_d A[r,d] * W1[h, coff+d]
// via split-bf16 3-pass MFMA (AhWh + AhWl + AlWh), fp32 accumulate.
//   blocks 0..63   (q): Eq[bo][h] = exp2(CSCALE*(acc + b1[h]))
//   blocks 64..575 (k): MASK-COMPACTED GEMM (inline ballot-prefix mask scan;
//     block owns compacted slots [jb0, jb0+64), exits if jb0 >= cnt[b]).
// 64x64 tile, 4 waves (2x2 grid of 32x32 wave-tiles), K-chunk 64.
// Blocks 576..591: Wf -> WfT transpose.
// ---------------------------------------------------------------------------
#define OFF_AH 0
#define OFF_AL 9216
#define OFF_WH 18432
#define OFF_WL 27648

__global__ __launch_bounds__(256, 4) void proj_kernel(
    const float* __restrict__ q, const float* __restrict__ k,
    const float* __restrict__ W1, const float* __restrict__ b1,
    const float* __restrict__ Wf, const int* __restrict__ mask,
    float* __restrict__ Eq, float* __restrict__ Ek4, float* __restrict__ WfT)
{
  __shared__ __align__(16) char smemRaw[36864];   // 36 KB
  __shared__ int idx_s[64];                       // gather window
  __shared__ int swtot[4];

  const int t  = threadIdx.x;
  const int bx = blockIdx.x;

  if (bx >= 576) {                 // ---- Wf transpose path ----
    float* smem = (float*)smemRaw;
    const int tt = bx - 576;
    const int tr = tt >> 2, tc = tt & 3;
#pragma unroll
    for (int p = 0; p < 4; ++p) {
      int idx2 = p * 256 + t;
      int row = idx2 >> 4, j = idx2 & 15;
      float4 vv = *(const float4*)(Wf + (size_t)(tr * 64 + row) * 256 + tc * 64 + j * 4);
      *(float4*)&smem[row * 68 + j * 4] = vv;
    }
    __syncthreads();
#pragma unroll
    for (int p = 0; p < 4; ++p) {
      int idx2 = p * 256 + t;
      int row = idx2 >> 4, j = idx2 & 15;
      float4 ov;
      ov.x = smem[(j * 4 + 0) * 68 + row];
      ov.y = smem[(j * 4 + 1) * 68 + row];
      ov.z = smem[(j * 4 + 2) * 68 + row];
      ov.w = smem[(j * 4 + 3) * 68 + row];
      *(float4*)(WfT + (size_t)(tc * 64 + row) * 256 + tr * 64 + j * 4) = ov;
    }
    return;
  }

  const int mt = bx >> 2;
  const int nt = bx & 3;
  const int h0 = nt * 64;
  const bool isq = (mt < 16);

  const int srow = t >> 4;           // staging rows: srow + {0,16,32,48}
  const int sc4  = t & 15;
  const int lane = t & 63, w = t >> 6;
  const int m0w = (w >> 1) * 32, n0w = (w & 1) * 32;
  const int lr = lane & 15, lg = lane >> 4;

  const float* src;
  int coff, bb = 0, jb0 = 0, cntb = 0;
  int rowg[4];

  if (isq) {
    src  = q + (size_t)(mt * 64) * DIM;
    coff = 0;
#pragma unroll
    for (int p = 0; p < 4; ++p) rowg[p] = srow + p * 16;
  } else {
    const int ki = mt - 16;          // 0..127
    bb  = ki >> 3;                   // batch
    jb0 = (ki & 7) * 64;             // compacted window start
    // ---- inline mask scan: thread t handles entries 2t, 2t+1 ----
    const int e0 = (mask[bb * NI + 2 * t] == 0);
    const int e1 = (mask[bb * NI + 2 * t + 1] == 0);
    const int ps = e0 + e1;
    int x = ps;
#pragma unroll
    for (int off = 1; off < 64; off <<= 1) {
      int y = __shfl_up(x, off, 64);
      if (lane >= off) x += y;
    }
    if (lane == 63) swtot[w] = x;
    if (t < 64) idx_s[t] = 0;        // safe default for tail rows
    __syncthreads();
    int woffv = 0;
#pragma unroll
    for (int w2 = 0; w2 < 4; ++w2) {
      int v_ = swtot[w2];
      if (w2 < w) woffv += v_;
      cntb += v_;
    }
    const int excl = woffv + x - ps;          // prefix before entry 2t
    const int p0 = excl, p1 = excl + e0;
    if (e0 && p0 >= jb0 && p0 < jb0 + 64) idx_s[p0 - jb0] = 2 * t;
    if (e1 && p1 >= jb0 && p1 < jb0 + 64) idx_s[p1 - jb0] = 2 * t + 1;
    __syncthreads();
    if (jb0 >= cntb) return;         // block-uniform: nothing to do
    src  = k + (size_t)bb * NI * DIM;
    coff = DIM;
#pragma unroll
    for (int p = 0; p < 4; ++p) rowg[p] = idx_s[srow + p * 16];
  }

  f32x4 acc[2][2] = {};

  float4 aR[4], wR[4];
#define LOADC(c0_)                                                              \
  _Pragma("unroll")                                                             \
  for (int p = 0; p < 4; ++p) {                                                 \
    aR[p] = *(const float4*)(src + (size_t)rowg[p] * DIM + (c0_) + sc4 * 4);    \
    wR[p] = *(const float4*)(W1 + (size_t)(h0 + srow + p * 16) * (2 * DIM) + coff + (c0_) + sc4 * 4); \
  }

  LOADC(0)

  for (int c = 0; c < 4; ++c) {
    // ---- convert chunk c (in regs) to bf16 hi/lo and stage to LDS ----
#pragma unroll
    for (int p = 0; p < 4; ++p) {
      int row = srow + p * 16;
      int boff = row * 144 + sc4 * 8;     // byte offset within each array
      unsigned int h0_, h1_, h2_, h3_;
      float l0, l1, l2, l3;
      split2(aR[p].x, h0_, l0); split2(aR[p].y, h1_, l1);
      split2(aR[p].z, h2_, l2); split2(aR[p].w, h3_, l3);
      *(U2*)(smemRaw + OFF_AH + boff) = { h0_ | (h1_ << 16), h2_ | (h3_ << 16) };
      *(U2*)(smemRaw + OFF_AL + boff) = { rne16(l0) | (rne16(l1) << 16),
                                          rne16(l2) | (rne16(l3) << 16) };
      split2(wR[p].x, h0_, l0); split2(wR[p].y, h1_, l1);
      split2(wR[p].z, h2_, l2); split2(wR[p].w, h3_, l3);
      *(U2*)(smemRaw + OFF_WH + boff) = { h0_ | (h1_ << 16), h2_ | (h3_ << 16) };
      *(U2*)(smemRaw + OFF_WL + boff) = { rne16(l0) | (rne16(l1) << 16),
                                          rne16(l2) | (rne16(l3) << 16) };
    }
    __syncthreads();

    if (c < 3) { LOADC((c + 1) * 64) }   // issue-early: flies under the MFMAs

    // ---- MFMA over this 64-wide K chunk: 2 k-steps of 32 ----
#pragma unroll
    for (int kk = 0; kk < 2; ++kk) {
      const int kb = kk * 64 + lg * 16;  // byte offset of this lane's 8 bf16
      bf16x8 ah[2], al[2], bh[2], bl[2];
#pragma unroll
      for (int mi = 0; mi < 2; ++mi) {
        int row = m0w + mi * 16 + lr;
        ah[mi] = __builtin_bit_cast(bf16x8, *(const u32x4*)(smemRaw + OFF_AH + row * 144 + kb));
        al[mi] = __builtin_bit_cast(bf16x8, *(const u32x4*)(smemRaw + OFF_AL + row * 144 + kb));
      }
#pragma unroll
      for (int ni = 0; ni < 2; ++ni) {
        int row = n0w + ni * 16 + lr;
        bh[ni] = __builtin_bit_cast(bf16x8, *(const u32x4*)(smemRaw + OFF_WH + row * 144 + kb));
        bl[ni] = __builtin_bit_cast(bf16x8, *(const u32x4*)(smemRaw + OFF_WL + row * 144 + kb));
      }
#pragma unroll
      for (int mi = 0; mi < 2; ++mi)
#pragma unroll
        for (int ni = 0; ni < 2; ++ni) {
          acc[mi][ni] = __builtin_amdgcn_mfma_f32_16x16x32_bf16(ah[mi], bh[ni], acc[mi][ni], 0, 0, 0);
          acc[mi][ni] = __builtin_amdgcn_mfma_f32_16x16x32_bf16(ah[mi], bl[ni], acc[mi][ni], 0, 0, 0);
          acc[mi][ni] = __builtin_amdgcn_mfma_f32_16x16x32_bf16(al[mi], bh[ni], acc[mi][ni], 0, 0, 0);
        }
    }
    __syncthreads();
  }

  // ---- epilogue. C/D layout (m89-verified): col(n)=lane&15, row(m)=(lane>>4)*4+reg
  if (isq) {
    const int r0 = mt * 64;
#pragma unroll
    for (int ni = 0; ni < 2; ++ni) {
      int h = h0 + n0w + ni * 16 + lr;
      float b1v = b1[h];
#pragma unroll
      for (int mi = 0; mi < 2; ++mi)
#pragma unroll
        for (int rg = 0; rg < 4; ++rg) {
          int r = r0 + m0w + mi * 16 + lg * 4 + rg;
          Eq[(size_t)r * DIM + h] =
              __builtin_amdgcn_exp2f((acc[mi][ni][rg] + b1v) * CSCALE);
        }
    }
  } else {
    const int lim = cntb - jb0;      // valid local rows in this window
#pragma unroll
    for (int mi = 0; mi < 2; ++mi)
#pragma unroll
      for (int rg = 0; rg < 4; ++rg) {
        int local = m0w + mi * 16 + lg * 4 + rg;
        if (local < lim) {
          int pos = jb0 + local;     // dense compacted slot
#pragma unroll
          for (int ni = 0; ni < 2; ++ni) {
            int h = h0 + n0w + ni * 16 + lr;
            Ek4[((size_t)(bb * 64 + (h >> 2)) * NI + pos) * 4 + (h & 3)] =
                __builtin_amdgcn_exp2f(acc[mi][ni][rg] * CSCALE);
          }
        }
      }
  }
}

__device__ __forceinline__ void f4arr(float4 v, float* a) {
  a[0] = v.x; a[1] = v.y; a[2] = v.z; a[3] = v.w;
}

// ---------------------------------------------------------------------------
// Kernel 2: ONE 1024-thread block per CU (grid 256), OT=4 o's per block.
// Halves per-CU cacheline traffic vs 2x512 blocks; 16 full waves, no dead
// lanes:
//  phase 1: 4 lanes/column, hq split x16, butterfly shfl_xor(1,2).
//  phase 3: 16 j's per wave.
//  phase 4: thread = (oo, d-quad, e-quarter); float4 WfT loads (64 vs 256
//           scalar); reduce over e-quarters via shfl_xor(16,32).
// ---------------------------------------------------------------------------
__global__ __launch_bounds__(1024, 4) void attn_kernel(
    const float* __restrict__ Eq, const float* __restrict__ Ek4,
    const float* __restrict__ v, const int* __restrict__ mask,
    const float* __restrict__ W2, const float* __restrict__ b2,
    const float* __restrict__ WfT, const float* __restrict__ bf,
    float* __restrict__ out, float* __restrict__ attn_out)
{
  __shared__ float sc[OT][NI];        // 8 KB (unnormalized p, then normalized)
  __shared__ int   idxs[NI];          // 2 KB
  __shared__ int   posa[NI];          // 2 KB
  __shared__ float qs[OT][DIM];       // 4 KB
  __shared__ float w2s[DIM];          // 1 KB
  __shared__ float pvp[16][OT][DIM];  // 64 KB
  __shared__ float o0[OT][DIM];       // 4 KB
  __shared__ float red8[16][OT];
  __shared__ float redw[16];
  __shared__ int   swtot8[8];

  const int t    = threadIdx.x;
  const int lane = t & 63;
  const int wid  = t >> 6;            // 0..15

  const int blk  = blockIdx.x;
  const int tile = (blk & 7) * 32 + (blk >> 3);   // XCD swizzle over 256
  const int b    = tile >> 4;
  const int bo0  = b * 64 + (tile & 15) * OT;

  // ---- inline mask scan (threads 0..511 map to columns) ----
  const int unm = (t < NI) ? ((mask[b * NI + t] == 0) ? 1 : 0) : 0;
  unsigned long long bal = __ballot(unm);
  int my = __popcll(bal & ((1ull << lane) - 1ull));
  if (lane == 0 && wid < 8) swtot8[wid] = __popcll(bal);

  // ---- stage Eq rows + W2 into LDS (disjoint thread groups) ----
  if (t < 256) {
    const int r = t >> 6, part = t & 63;
    *(float4*)&qs[r][part * 4] =
        *(const float4*)(Eq + (size_t)(bo0 + r) * DIM + part * 4);
  } else if (t < 320) {
    const int part = t - 256;
    *(float4*)&w2s[part * 4] = *(const float4*)(W2 + part * 4);
  }

  // ---- sumW2 ----
  float partial = (t < DIM) ? W2[t] : 0.f;
#pragma unroll
  for (int off = 32; off >= 1; off >>= 1) partial += __shfl_xor(partial, off, 64);
  if (lane == 0) redw[wid] = partial;
  __syncthreads();                               // B1

  int cntb = 0, woffv = 0;
#pragma unroll
  for (int w = 0; w < 8; ++w) {
    int v_ = swtot8[w];
    if (w < wid) woffv += v_;
    cntb += v_;
  }
  const int myPos = unm ? (woffv + my) : -1;
  if (unm) idxs[myPos] = t;
  if (t < NI) posa[t] = myPos;

  float sumw2 = 0.f;
#pragma unroll
  for (int w = 0; w < 16; ++w) sumw2 += redw[w];
  const float base = sumw2 + b2[0];

  // ---- phase 1: 4 lanes/column; hq split x16; 16 waves x 16 cols/pass ----
  const float4* kb4 = (const float4*)Ek4 + (size_t)b * 64 * NI;  // [hq*NI + j]
  const int quad = lane >> 2;                    // 0..15 (column within wave)
  const int hqb  = (lane & 3) << 4;              // hq subrange start
  float psum[OT] = {};
  float pval[2][OT];                             // per-pass p (for normalize)
  int   pcol[2] = {-1, -1};

#pragma unroll
  for (int pass = 0; pass < 2; ++pass) {
    const int pb = pass << 8;
    if (pb + (wid << 4) < cntb) {                // wave-uniform
      const int jc0 = pb + (wid << 4) + quad;
      const bool act = jc0 < cntb;
      const int jc = act ? jc0 : (cntb - 1);
      float a[OT] = {};
#pragma unroll 4
      for (int hh = 0; hh < 16; ++hh) {
        const int hq = hqb + hh;
        float4 kq = kb4[(size_t)hq * NI + jc];
        float wr[4], kv[4];
        f4arr(*(const float4*)&w2s[hq * 4], wr);
        f4arr(kq, kv);
        float qr[OT][4];
#pragma unroll
        for (int r = 0; r < OT; ++r) f4arr(*(const float4*)&qs[r][hq * 4], qr[r]);
#pragma unroll
        for (int pr = 0; pr < 2; ++pr) {         // pairs (0,1), (2,3)
          const int ea = pr * 2, eb = pr * 2 + 1;
#pragma unroll
          for (int r = 0; r < OT; ++r) {
            float A = fmaf(qr[r][ea], kv[ea], 1.f);
            float B = fmaf(qr[r][eb], kv[eb], 1.f);
            float N = fmaf(wr[eb], A, wr[ea] * B);
            a[r] = fmaf(N, __builtin_amdgcn_rcpf(A * B), a[r]);
          }
        }
      }
#pragma unroll
      for (int r = 0; r < OT; ++r) {             // combine 4 hq subranges
        a[r] += __shfl_xor(a[r], 1, 64);
        a[r] += __shfl_xor(a[r], 2, 64);
        float s = act ? (base - 2.f * a[r]) : -INFINITY;
        float p = __builtin_amdgcn_exp2f(s * 1.4426950408889634f);
        psum[r] += p;
        pval[pass][r] = p;
        sc[r][jc0] = p;                          // 4 dup lanes, same value
      }
      pcol[pass] = jc0;
    }
  }

  // ---- phase 2: denominator (x4 overcount -> scale 0.25) ----
#pragma unroll
  for (int off = 32; off >= 1; off >>= 1)
#pragma unroll
    for (int r = 0; r < OT; ++r) psum[r] += __shfl_xor(psum[r], off, 64);
  if (lane == 0)
#pragma unroll
    for (int r = 0; r < OT; ++r) red8[wid][r] = psum[r];
  __syncthreads();                               // B2
  float inv[OT];
#pragma unroll
  for (int r = 0; r < OT; ++r) {
    float ssr = 0.f;
#pragma unroll
    for (int w = 0; w < 16; ++w) ssr += red8[w][r];
    inv[r] = __builtin_amdgcn_rcpf(0.25f * ssr);
  }
  // normalize own columns (write from registers; dup lanes same value)
#pragma unroll
  for (int pass = 0; pass < 2; ++pass) {
    if (pcol[pass] >= 0) {
#pragma unroll
      for (int r = 0; r < OT; ++r) sc[r][pcol[pass]] = pval[pass][r] * inv[r];
    }
  }
  __syncthreads();                               // B3

  // ---- attn_out scatter-back: thread t -> column t&511, rows rb,rb+1 ----
  {
    const int i = t & (NI - 1);
    const int rb = (t >> 9) << 1;                // 0 or 2
    const int pi = posa[i];
#pragma unroll
    for (int rr = 0; rr < 2; ++rr) {
      float wv = (pi >= 0) ? sc[rb + rr][pi] : 0.f;
      attn_out[(size_t)(bo0 + rb + rr) * NI + i] = wv;
    }
  }

  // ---- phase 3: PV. wave wid owns j in [wid*16,+16) (+256 tail pass) ----
  {
    float4 av[OT] = {};
    const float4* vb4 = (const float4*)(v + (size_t)b * NI * DIM);
#pragma unroll
    for (int pass = 0; pass < 2; ++pass) {
      const int start = (pass << 8) + (wid << 4);
      const int jend = min(start + 16, cntb);
#pragma unroll 4
      for (int jb = start; jb < jend; ++jb) {
        int row = idxs[jb];                      // LDS broadcast (uniform)
        float sa[OT];
#pragma unroll
        for (int r = 0; r < OT; ++r) sa[r] = sc[r][jb];
        float4 vv = vb4[(size_t)row * 64 + lane];
#pragma unroll
        for (int r = 0; r < OT; ++r) {
          av[r].x = fmaf(sa[r], vv.x, av[r].x);
          av[r].y = fmaf(sa[r], vv.y, av[r].y);
          av[r].z = fmaf(sa[r], vv.z, av[r].z);
          av[r].w = fmaf(sa[r], vv.w, av[r].w);
        }
      }
    }
#pragma unroll
    for (int r = 0; r < OT; ++r)
      *(float4*)&pvp[wid][r][lane * 4] = av[r];  // idle waves store zeros
  }
  __syncthreads();                               // B4
  {
    const int oo = t >> 8, d = t & 255;          // all 1024 threads
    float sacc = 0.f;
#pragma unroll
    for (int w = 0; w < 16; ++w) sacc += pvp[w][oo][d];
    o0[oo][d] = sacc;
  }
  __syncthreads();                               // B5

  // ---- phase 4: wave = (oo, d-block); lane = (e-quarter, d-quad) ----
  {
    const int oo   = wid >> 2;                   // 0..3
    const int dblk = (wid & 3) * 64;
    const int dq   = lane & 15;
    const int eg   = lane >> 4;                  // 0..3 e-quarter
    const int d0   = dblk + dq * 4;
    const int e0   = eg * 64;
    float f[4] = {};
#pragma unroll 8
    for (int ee = 0; ee < 64; ++ee) {
      const int e = e0 + ee;
      float wv[4];
      f4arr(*(const float4*)&WfT[(size_t)e * DIM + d0], wv);
      float ov = o0[oo][e];
#pragma unroll
      for (int c = 0; c < 4; ++c) f[c] = fmaf(ov, wv[c], f[c]);
    }
#pragma unroll
    for (int c = 0; c < 4; ++c) {
      f[c] += __shfl_xor(f[c], 16, 64);
      f[c] += __shfl_xor(f[c], 32, 64);
    }
    if (lane < 16) {
      float bv[4];
      f4arr(*(const float4*)(bf + d0), bv);
      float4 ov4;
      float r0 = f[0] + bv[0]; ov4.x = (r0 >= 0.f) ? r0 : NEG_SLOPE * r0;
      float r1 = f[1] + bv[1]; ov4.y = (r1 >= 0.f) ? r1 : NEG_SLOPE * r1;
      float r2 = f[2] + bv[2]; ov4.z = (r2 >= 0.f) ? r2 : NEG_SLOPE * r2;
      float r3 = f[3] + bv[3]; ov4.w = (r3 >= 0.f) ? r3 : NEG_SLOPE * r3;
      *(float4*)(out + (size_t)(bo0 + oo) * DIM + d0) = ov4;
    }
  }
}

// ---------------------------------------------------------------------------
extern "C" void kernel_launch(void* const* d_in, const int* in_sizes, int n_in,
                              void* d_out, int out_size, void* d_ws, size_t ws_size,
                              hipStream_t stream) {
  const float* q    = (const float*)d_in[0];
  const float* k    = (const float*)d_in[1];
  const float* v    = (const float*)d_in[2];
  const int*   mask = (const int*)d_in[3];
  const float* W1   = (const float*)d_in[4];
  const float* b1   = (const float*)d_in[5];
  const float* W2   = (const float*)d_in[6];
  const float* b2   = (const float*)d_in[7];
  const float* Wf   = (const float*)d_in[8];
  const float* bf   = (const float*)d_in[9];

  float* out      = (float*)d_out;                    // (16,64,256)
  float* attn_out = out + (size_t)BATCH * NO * DIM;   // (16,64,512)

  float* Eq   = (float*)d_ws;                         // 1024 x 256
  float* Ek4  = Eq + (size_t)BATCH * NO * DIM;        // 16 x 64 x 512 x 4
  float* WfT  = Ek4 + (size_t)BATCH * DIM * NI;       // 256 x 256

  proj_kernel<<<592, 256, 0, stream>>>(q, k, W1, b1, Wf, mask, Eq, Ek4, WfT);
  attn_kernel<<<(BATCH * NO) / OT, 1024, 0, stream>>>(Eq, Ek4, v, mask,
                                                      W2, b2, WfT, bf, out, attn_out);
}

// Round 7
// 121.201 us; speedup vs baseline: 1.0180x; 1.0180x over previous
//
#include <hip/hip_runtime.h>
#include <math.h>

#define DIM 256
#define BATCH 16
#define NO 64
#define NI 512
#define NIP 528                     // padded Ek4 inner extent: hq-stride 8448 B
                                    // (breaks 8 KB power-of-2 L2 channel camping)
#define WFT_LD 272                  // padded WfT row stride (1088 B, not 1 KB)
#define NEG_SLOPE 0.01f
#define CSCALE 2.885390081777927f   // 2*log2(e): tanh(x) = 1 - 2/(exp2(CSCALE*x)+1)
#define OT 2                        // o's per attn block

typedef float f32x4 __attribute__((ext_vector_type(4)));
typedef __bf16 bf16x8 __attribute__((ext_vector_type(8)));
typedef unsigned int u32x4 __attribute__((ext_vector_type(4)));

// ---------------------------------------------------------------------------
// split f32 -> bf16 hi (RNE, returned as low-16 bits) + exact f32 residual
// ---------------------------------------------------------------------------
__device__ __forceinline__ void split2(float f, unsigned int& hi16, float& lo) {
  unsigned int u = __builtin_bit_cast(unsigned int, f);
  unsigned int h = (u + 0x7FFFu + ((u >> 16) & 1u)) & 0xFFFF0000u; // RNE bf16, as f32 bits
  hi16 = h >> 16;
  lo = f - __builtin_bit_cast(float, h);   // exact (Sterbenz)
}
__device__ __forceinline__ unsigned int rne16(float f) {
  unsigned int u = __builtin_bit_cast(unsigned int, f);
  return (u + 0x7FFFu + ((u >> 16) & 1u)) >> 16;
}

struct __align__(8) U2 { unsigned int x, y; };

// ---------------------------------------------------------------------------
// Kernel 1 (blocks 0..575): GEMM  out[r,h] = sum_d A[r,d] * W1[h, coff+d]
// via split-bf16 3-pass MFMA (AhWh + AhWl + AlWh), fp32 accumulate.
//   blocks 0..63   (q): Eq[bo][h] = exp2(CSCALE*(acc + b1[h]))
//   blocks 64..575 (k): MASK-COMPACTED GEMM (inline ballot-prefix mask scan;
//     block owns compacted slots [jb0, jb0+64), exits if jb0 >= cnt[b]).
//     Ek4 uses PADDED inner extent NIP (channel decamping).
// 64x64 tile, 4 waves (2x2 grid of 32x32 wave-tiles), K-chunk 64.
// Blocks 576..591: Wf -> WfT transpose (PADDED row stride WFT_LD).
// ---------------------------------------------------------------------------
#define OFF_AH 0
#define OFF_AL 9216
#define OFF_WH 18432
#define OFF_WL 27648

__global__ __launch_bounds__(256, 4) void proj_kernel(
    const float* __restrict__ q, const float* __restrict__ k,
    const float* __restrict__ W1, const float* __restrict__ b1,
    const float* __restrict__ Wf, const int* __restrict__ mask,
    float* __restrict__ Eq, float* __restrict__ Ek4, float* __restrict__ WfT)
{
  __shared__ __align__(16) char smemRaw[36864];   // 36 KB
  __shared__ int idx_s[64];                       // gather window
  __shared__ int swtot[4];

  const int t  = threadIdx.x;
  const int bx = blockIdx.x;

  if (bx >= 576) {                 // ---- Wf transpose path ----
    float* smem = (float*)smemRaw;
    const int tt = bx - 576;
    const int tr = tt >> 2, tc = tt & 3;
#pragma unroll
    for (int p = 0; p < 4; ++p) {
      int idx2 = p * 256 + t;
      int row = idx2 >> 4, j = idx2 & 15;
      float4 vv = *(const float4*)(Wf + (size_t)(tr * 64 + row) * 256 + tc * 64 + j * 4);
      *(float4*)&smem[row * 68 + j * 4] = vv;
    }
    __syncthreads();
#pragma unroll
    for (int p = 0; p < 4; ++p) {
      int idx2 = p * 256 + t;
      int row = idx2 >> 4, j = idx2 & 15;
      float4 ov;
      ov.x = smem[(j * 4 + 0) * 68 + row];
      ov.y = smem[(j * 4 + 1) * 68 + row];
      ov.z = smem[(j * 4 + 2) * 68 + row];
      ov.w = smem[(j * 4 + 3) * 68 + row];
      *(float4*)(WfT + (size_t)(tc * 64 + row) * WFT_LD + tr * 64 + j * 4) = ov;
    }
    return;
  }

  const int mt = bx >> 2;
  const int nt = bx & 3;
  const int h0 = nt * 64;
  const bool isq = (mt < 16);

  const int srow = t >> 4;           // staging rows: srow + {0,16,32,48}
  const int sc4  = t & 15;
  const int lane = t & 63, w = t >> 6;
  const int m0w = (w >> 1) * 32, n0w = (w & 1) * 32;
  const int lr = lane & 15, lg = lane >> 4;

  const float* src;
  int coff, bb = 0, jb0 = 0, cntb = 0;
  int rowg[4];

  if (isq) {
    src  = q + (size_t)(mt * 64) * DIM;
    coff = 0;
#pragma unroll
    for (int p = 0; p < 4; ++p) rowg[p] = srow + p * 16;
  } else {
    const int ki = mt - 16;          // 0..127
    bb  = ki >> 3;                   // batch
    jb0 = (ki & 7) * 64;             // compacted window start
    // ---- inline mask scan: thread t handles entries 2t, 2t+1 ----
    const int e0 = (mask[bb * NI + 2 * t] == 0);
    const int e1 = (mask[bb * NI + 2 * t + 1] == 0);
    const int ps = e0 + e1;
    int x = ps;
#pragma unroll
    for (int off = 1; off < 64; off <<= 1) {
      int y = __shfl_up(x, off, 64);
      if (lane >= off) x += y;
    }
    if (lane == 63) swtot[w] = x;
    if (t < 64) idx_s[t] = 0;        // safe default for tail rows
    __syncthreads();
    int woffv = 0;
#pragma unroll
    for (int w2 = 0; w2 < 4; ++w2) {
      int v_ = swtot[w2];
      if (w2 < w) woffv += v_;
      cntb += v_;
    }
    const int excl = woffv + x - ps;          // prefix before entry 2t
    const int p0 = excl, p1 = excl + e0;
    if (e0 && p0 >= jb0 && p0 < jb0 + 64) idx_s[p0 - jb0] = 2 * t;
    if (e1 && p1 >= jb0 && p1 < jb0 + 64) idx_s[p1 - jb0] = 2 * t + 1;
    __syncthreads();
    if (jb0 >= cntb) return;         // block-uniform: nothing to do
    src  = k + (size_t)bb * NI * DIM;
    coff = DIM;
#pragma unroll
    for (int p = 0; p < 4; ++p) rowg[p] = idx_s[srow + p * 16];
  }

  f32x4 acc[2][2] = {};

  float4 aR[4], wR[4];
#define LOADC(c0_)                                                              \
  _Pragma("unroll")                                                             \
  for (int p = 0; p < 4; ++p) {                                                 \
    aR[p] = *(const float4*)(src + (size_t)rowg[p] * DIM + (c0_) + sc4 * 4);    \
    wR[p] = *(const float4*)(W1 + (size_t)(h0 + srow + p * 16) * (2 * DIM) + coff + (c0_) + sc4 * 4); \
  }

  LOADC(0)

  for (int c = 0; c < 4; ++c) {
    // ---- convert chunk c (in regs) to bf16 hi/lo and stage to LDS ----
#pragma unroll
    for (int p = 0; p < 4; ++p) {
      int row = srow + p * 16;
      int boff = row * 144 + sc4 * 8;     // byte offset within each array
      unsigned int h0_, h1_, h2_, h3_;
      float l0, l1, l2, l3;
      split2(aR[p].x, h0_, l0); split2(aR[p].y, h1_, l1);
      split2(aR[p].z, h2_, l2); split2(aR[p].w, h3_, l3);
      *(U2*)(smemRaw + OFF_AH + boff) = { h0_ | (h1_ << 16), h2_ | (h3_ << 16) };
      *(U2*)(smemRaw + OFF_AL + boff) = { rne16(l0) | (rne16(l1) << 16),
                                          rne16(l2) | (rne16(l3) << 16) };
      split2(wR[p].x, h0_, l0); split2(wR[p].y, h1_, l1);
      split2(wR[p].z, h2_, l2); split2(wR[p].w, h3_, l3);
      *(U2*)(smemRaw + OFF_WH + boff) = { h0_ | (h1_ << 16), h2_ | (h3_ << 16) };
      *(U2*)(smemRaw + OFF_WL + boff) = { rne16(l0) | (rne16(l1) << 16),
                                          rne16(l2) | (rne16(l3) << 16) };
    }
    __syncthreads();

    if (c < 3) { LOADC((c + 1) * 64) }   // issue-early: flies under the MFMAs

    // ---- MFMA over this 64-wide K chunk: 2 k-steps of 32 ----
#pragma unroll
    for (int kk = 0; kk < 2; ++kk) {
      const int kb = kk * 64 + lg * 16;  // byte offset of this lane's 8 bf16
      bf16x8 ah[2], al[2], bh[2], bl[2];
#pragma unroll
      for (int mi = 0; mi < 2; ++mi) {
        int row = m0w + mi * 16 + lr;
        ah[mi] = __builtin_bit_cast(bf16x8, *(const u32x4*)(smemRaw + OFF_AH + row * 144 + kb));
        al[mi] = __builtin_bit_cast(bf16x8, *(const u32x4*)(smemRaw + OFF_AL + row * 144 + kb));
      }
#pragma unroll
      for (int ni = 0; ni < 2; ++ni) {
        int row = n0w + ni * 16 + lr;
        bh[ni] = __builtin_bit_cast(bf16x8, *(const u32x4*)(smemRaw + OFF_WH + row * 144 + kb));
        bl[ni] = __builtin_bit_cast(bf16x8, *(const u32x4*)(smemRaw + OFF_WL + row * 144 + kb));
      }
#pragma unroll
      for (int mi = 0; mi < 2; ++mi)
#pragma unroll
        for (int ni = 0; ni < 2; ++ni) {
          acc[mi][ni] = __builtin_amdgcn_mfma_f32_16x16x32_bf16(ah[mi], bh[ni], acc[mi][ni], 0, 0, 0);
          acc[mi][ni] = __builtin_amdgcn_mfma_f32_16x16x32_bf16(ah[mi], bl[ni], acc[mi][ni], 0, 0, 0);
          acc[mi][ni] = __builtin_amdgcn_mfma_f32_16x16x32_bf16(al[mi], bh[ni], acc[mi][ni], 0, 0, 0);
        }
    }
    __syncthreads();
  }

  // ---- epilogue. C/D layout (m89-verified): col(n)=lane&15, row(m)=(lane>>4)*4+reg
  if (isq) {
    const int r0 = mt * 64;
#pragma unroll
    for (int ni = 0; ni < 2; ++ni) {
      int h = h0 + n0w + ni * 16 + lr;
      float b1v = b1[h];
#pragma unroll
      for (int mi = 0; mi < 2; ++mi)
#pragma unroll
        for (int rg = 0; rg < 4; ++rg) {
          int r = r0 + m0w + mi * 16 + lg * 4 + rg;
          Eq[(size_t)r * DIM + h] =
              __builtin_amdgcn_exp2f((acc[mi][ni][rg] + b1v) * CSCALE);
        }
    }
  } else {
    const int lim = cntb - jb0;      // valid local rows in this window
#pragma unroll
    for (int mi = 0; mi < 2; ++mi)
#pragma unroll
      for (int rg = 0; rg < 4; ++rg) {
        int local = m0w + mi * 16 + lg * 4 + rg;
        if (local < lim) {
          int pos = jb0 + local;     // dense compacted slot
#pragma unroll
          for (int ni = 0; ni < 2; ++ni) {
            int h = h0 + n0w + ni * 16 + lr;
            Ek4[((size_t)(bb * 64 + (h >> 2)) * NIP + pos) * 4 + (h & 3)] =
                __builtin_amdgcn_exp2f(acc[mi][ni][rg] * CSCALE);
          }
        }
      }
  }
}

__device__ __forceinline__ void f4arr(float4 v, float* a) {
  a[0] = v.x; a[1] = v.y; a[2] = v.z; a[3] = v.w;
}

// ---------------------------------------------------------------------------
// Kernel 2: one block (512 threads) per (b, o-pair). Grid 512. XCD-swizzled.
// Round-2 structure; Ek4/WfT reads use the PADDED strides (NIP / WFT_LD).
// ---------------------------------------------------------------------------
__global__ __launch_bounds__(512, 4) void attn_kernel(
    const float* __restrict__ Eq, const float* __restrict__ Ek4,
    const float* __restrict__ v, const int* __restrict__ mask,
    const float* __restrict__ W2, const float* __restrict__ b2,
    const float* __restrict__ WfT, const float* __restrict__ bf,
    float* __restrict__ out, float* __restrict__ attn_out)
{
  __shared__ float sc[OT][NI];        // 4 KB (compacted attn weights)
  __shared__ int   idxs[NI];          // 2 KB
  __shared__ float pvp[8][OT][DIM];   // 16 KB
  __shared__ float o0[OT][DIM];       // 2 KB
  __shared__ float red4[8][OT];
  __shared__ float redw[8];
  __shared__ int   swtot8[8];

  const int t    = threadIdx.x;
  const int lane = t & 63;
  const int wid  = t >> 6;

  const int blk  = blockIdx.x;
  const int tile = (blk & 7) * 64 + (blk >> 3);   // XCD swizzle
  const int b    = tile >> 5;
  const int bo0  = b * 64 + (tile & 31) * OT;

  // ---- inline mask scan ----
  const int unm = (mask[b * NI + t] == 0) ? 1 : 0;
  unsigned long long bal = __ballot(unm);
  int my = __popcll(bal & ((1ull << lane) - 1ull));
  if (lane == 0) swtot8[wid] = __popcll(bal);

  // ---- sumW2 (overlapped with scan barrier) ----
  float partial = (t < DIM) ? W2[t] : 0.f;
#pragma unroll
  for (int off = 32; off >= 1; off >>= 1) partial += __shfl_xor(partial, off, 64);
  if (lane == 0) redw[wid] = partial;
  __syncthreads();

  int cntb = 0, woffv = 0;
#pragma unroll
  for (int w = 0; w < 8; ++w) {
    int v_ = swtot8[w];
    if (w < wid) woffv += v_;
    cntb += v_;
  }
  const int myPos = unm ? (woffv + my) : -1;
  if (unm) idxs[myPos] = t;          // read in phase 3, after barriers

  float sumw2 = 0.f;
#pragma unroll
  for (int w = 0; w < 8; ++w) sumw2 += redw[w];
  const float base = sumw2 + b2[0];

  // ---- phase 1: scores for compacted column j = t (paired-rcp) ----
  const int j = t;
  const bool active = (j < cntb);
  const int jc = active ? j : (cntb > 0 ? cntb - 1 : 0);   // clamped safe index
  const float4* kb4 = (const float4*)Ek4 + (size_t)b * 64 * NIP;  // [hq*NIP + j]
  const float* qrow0 = Eq + (size_t)(bo0 + 0) * DIM;
  const float* qrow1 = Eq + (size_t)(bo0 + 1) * DIM;

  float acc0 = 0.f, acc1 = 0.f;
  if (wid * 64 < cntb) {                 // wave-uniform skip of dead waves
#pragma unroll 8
    for (int hq = 0; hq < 64; ++hq) {
      float4 kq = kb4[(size_t)hq * NIP + jc];
      float wr[4], q0r[4], q1r[4], kv[4];
      f4arr(*(const float4*)(W2 + hq * 4), wr);      // wave-uniform -> s_load
      f4arr(*(const float4*)(qrow0 + hq * 4), q0r);
      f4arr(*(const float4*)(qrow1 + hq * 4), q1r);
      f4arr(kq, kv);
#pragma unroll
      for (int pr = 0; pr < 2; ++pr) {               // pairs (0,1), (2,3)
        const int ea = pr * 2, eb = pr * 2 + 1;
        float A0 = fmaf(q0r[ea], kv[ea], 1.f);
        float B0 = fmaf(q0r[eb], kv[eb], 1.f);
        float N0 = fmaf(wr[eb], A0, wr[ea] * B0);
        acc0 = fmaf(N0, __builtin_amdgcn_rcpf(A0 * B0), acc0);
        float A1 = fmaf(q1r[ea], kv[ea], 1.f);
        float B1 = fmaf(q1r[eb], kv[eb], 1.f);
        float N1 = fmaf(wr[eb], A1, wr[ea] * B1);
        acc1 = fmaf(N1, __builtin_amdgcn_rcpf(A1 * B1), acc1);
      }
    }
  }

  float s0 = active ? (base - 2.f * acc0) : -INFINITY;
  float s1 = active ? (base - 2.f * acc1) : -INFINITY;

  // ---- phase 2: softmax over compacted set, no max-subtraction ----
  float p0 = __builtin_amdgcn_exp2f(s0 * 1.4426950408889634f);
  float p1 = __builtin_amdgcn_exp2f(s1 * 1.4426950408889634f);
  float ps0 = p0, ps1 = p1;
#pragma unroll
  for (int off = 32; off >= 1; off >>= 1) {
    ps0 += __shfl_xor(ps0, off, 64);
    ps1 += __shfl_xor(ps1, off, 64);
  }
  __syncthreads();               // redw reads done; red4 safe
  if (lane == 0) { red4[wid][0] = ps0; red4[wid][1] = ps1; }
  __syncthreads();
  float ss0 = 0.f, ss1 = 0.f;
#pragma unroll
  for (int w = 0; w < 8; ++w) { ss0 += red4[w][0]; ss1 += red4[w][1]; }
  const float a0 = p0 * __builtin_amdgcn_rcpf(ss0);
  const float a1 = p1 * __builtin_amdgcn_rcpf(ss1);
  sc[0][j] = a0;                 // compacted slot (0 for inactive j)
  sc[1][j] = a1;
  __syncthreads();

  // attn_out scatter-back: original column i = t; masked -> exact 0
  {
    float w0 = (myPos >= 0) ? sc[0][myPos] : 0.f;
    float w1 = (myPos >= 0) ? sc[1][myPos] : 0.f;
    attn_out[(size_t)(bo0 + 0) * NI + t] = w0;
    attn_out[(size_t)(bo0 + 1) * NI + t] = w1;
  }

  // ---- phase 3: PV over compacted rows. wave wid: j in [wid*64, +64)∩cnt ----
  {
    const int d4 = lane;
    float4 av0 = {0.f, 0.f, 0.f, 0.f};
    float4 av1 = {0.f, 0.f, 0.f, 0.f};
    const float4* vb4 = (const float4*)(v + (size_t)b * NI * DIM);
    const int jend = min(wid * 64 + 64, cntb);
#pragma unroll 4
    for (int jb = wid * 64; jb < jend; ++jb) {
      int row = idxs[jb];                      // LDS broadcast (uniform)
      float sa0 = sc[0][jb], sa1 = sc[1][jb];  // LDS broadcast
      float4 vv = vb4[(size_t)row * 64 + d4];
      av0.x = fmaf(sa0, vv.x, av0.x);
      av0.y = fmaf(sa0, vv.y, av0.y);
      av0.z = fmaf(sa0, vv.z, av0.z);
      av0.w = fmaf(sa0, vv.w, av0.w);
      av1.x = fmaf(sa1, vv.x, av1.x);
      av1.y = fmaf(sa1, vv.y, av1.y);
      av1.z = fmaf(sa1, vv.z, av1.z);
      av1.w = fmaf(sa1, vv.w, av1.w);
    }
    *(float4*)&pvp[wid][0][d4 * 4] = av0;      // dead waves store zeros
    *(float4*)&pvp[wid][1][d4 * 4] = av1;
  }
  __syncthreads();
  {
    int oo = t >> 8, d = t & 255;
    float sacc = 0.f;
#pragma unroll
    for (int w = 0; w < 8; ++w) sacc += pvp[w][oo][d];
    o0[oo][d] = sacc;
  }
  __syncthreads();

  // ---- phase 4: threads t<256 compute BOTH o's, one WfT column load ----
  if (t < DIM) {
    const int d = t;
    float f0 = 0.f, f1 = 0.f;
#pragma unroll 8
    for (int e4 = 0; e4 < 64; ++e4) {
      float oa[4], ob[4];
      f4arr(*(const float4*)&o0[0][e4 * 4], oa);
      f4arr(*(const float4*)&o0[1][e4 * 4], ob);
#pragma unroll
      for (int c = 0; c < 4; ++c) {
        float wv = WfT[(size_t)(e4 * 4 + c) * WFT_LD + d];
        f0 = fmaf(oa[c], wv, f0);
        f1 = fmaf(ob[c], wv, f1);
      }
    }
    float bfv = bf[d];
    f0 += bfv; f1 += bfv;
    f0 = (f0 >= 0.f) ? f0 : NEG_SLOPE * f0;
    f1 = (f1 >= 0.f) ? f1 : NEG_SLOPE * f1;
    out[(size_t)(bo0 + 0) * DIM + d] = f0;
    out[(size_t)(bo0 + 1) * DIM + d] = f1;
  }
}

// ---------------------------------------------------------------------------
extern "C" void kernel_launch(void* const* d_in, const int* in_sizes, int n_in,
                              void* d_out, int out_size, void* d_ws, size_t ws_size,
                              hipStream_t stream) {
  const float* q    = (const float*)d_in[0];
  const float* k    = (const float*)d_in[1];
  const float* v    = (const float*)d_in[2];
  const int*   mask = (const int*)d_in[3];
  const float* W1   = (const float*)d_in[4];
  const float* b1   = (const float*)d_in[5];
  const float* W2   = (const float*)d_in[6];
  const float* b2   = (const float*)d_in[7];
  const float* Wf   = (const float*)d_in[8];
  const float* bf   = (const float*)d_in[9];

  float* out      = (float*)d_out;                    // (16,64,256)
  float* attn_out = out + (size_t)BATCH * NO * DIM;   // (16,64,512)

  float* Eq   = (float*)d_ws;                         // 1024 x 256
  float* Ek4  = Eq + (size_t)BATCH * NO * DIM;        // 16 x 64 x NIP x 4
  float* WfT  = Ek4 + (size_t)BATCH * 64 * NIP * 4;   // 256 x WFT_LD

  proj_kernel<<<592, 256, 0, stream>>>(q, k, W1, b1, Wf, mask, Eq, Ek4, WfT);
  attn_kernel<<<(BATCH * NO) / OT, 512, 0, stream>>>(Eq, Ek4, v, mask,
                                                     W2, b2, WfT, bf, out, attn_out);
}

// Round 8
// 120.962 us; speedup vs baseline: 1.0200x; 1.0020x over previous
//
#include <hip/hip_runtime.h>
#include <math.h>

#define DIM 256
#define BATCH 16
#define NO 64
#define NI 512
#define NIP 528                     // padded Ek4 inner extent (8448 B hq-stride)
#define WFT_LD 272                  // padded WfT row stride (1088 B)
#define NEG_SLOPE 0.01f
#define CSCALE 2.885390081777927f   // 2*log2(e): tanh(x) = 1 - 2/(exp2(CSCALE*x)+1)
#define OT 2                        // o's per attn block

typedef float f32x4 __attribute__((ext_vector_type(4)));
typedef __bf16 bf16x8 __attribute__((ext_vector_type(8)));
typedef unsigned int u32x4 __attribute__((ext_vector_type(4)));

// ---------------------------------------------------------------------------
// split f32 -> bf16 hi (RNE, returned as low-16 bits) + exact f32 residual
// ---------------------------------------------------------------------------
__device__ __forceinline__ void split2(float f, unsigned int& hi16, float& lo) {
  unsigned int u = __builtin_bit_cast(unsigned int, f);
  unsigned int h = (u + 0x7FFFu + ((u >> 16) & 1u)) & 0xFFFF0000u; // RNE bf16, as f32 bits
  hi16 = h >> 16;
  lo = f - __builtin_bit_cast(float, h);   // exact (Sterbenz)
}
__device__ __forceinline__ unsigned int rne16(float f) {
  unsigned int u = __builtin_bit_cast(unsigned int, f);
  return (u + 0x7FFFu + ((u >> 16) & 1u)) >> 16;
}

struct __align__(8) U2 { unsigned int x, y; };

// ---------------------------------------------------------------------------
// Kernel 1 (blocks 0..575): GEMM  out[r,h] = sum_d A[r,d] * W1[h, coff+d]
// via split-bf16 3-pass MFMA (AhWh + AhWl + AlWh), fp32 accumulate.
//   blocks 0..63   (q): Eq[bo][h] = exp2(CSCALE*(acc + b1[h]))
//   blocks 64..575 (k): MASK-COMPACTED GEMM (inline ballot-prefix mask scan;
//     block owns compacted slots [jb0, jb0+64), exits if jb0 >= cnt[b]).
// 64x64 tile, 4 waves (2x2 grid of 32x32 wave-tiles), K-chunk 64.
// Blocks 576..591: Wf -> WfT transpose (padded row stride WFT_LD).
// ---------------------------------------------------------------------------
#define OFF_AH 0
#define OFF_AL 9216
#define OFF_WH 18432
#define OFF_WL 27648

__global__ __launch_bounds__(256, 4) void proj_kernel(
    const float* __restrict__ q, const float* __restrict__ k,
    const float* __restrict__ W1, const float* __restrict__ b1,
    const float* __restrict__ Wf, const int* __restrict__ mask,
    float* __restrict__ Eq, float* __restrict__ Ek4, float* __restrict__ WfT)
{
  __shared__ __align__(16) char smemRaw[36864];   // 36 KB
  __shared__ int idx_s[64];                       // gather window
  __shared__ int swtot[4];

  const int t  = threadIdx.x;
  const int bx = blockIdx.x;

  if (bx >= 576) {                 // ---- Wf transpose path ----
    float* smem = (float*)smemRaw;
    const int tt = bx - 576;
    const int tr = tt >> 2, tc = tt & 3;
#pragma unroll
    for (int p = 0; p < 4; ++p) {
      int idx2 = p * 256 + t;
      int row = idx2 >> 4, j = idx2 & 15;
      float4 vv = *(const float4*)(Wf + (size_t)(tr * 64 + row) * 256 + tc * 64 + j * 4);
      *(float4*)&smem[row * 68 + j * 4] = vv;
    }
    __syncthreads();
#pragma unroll
    for (int p = 0; p < 4; ++p) {
      int idx2 = p * 256 + t;
      int row = idx2 >> 4, j = idx2 & 15;
      float4 ov;
      ov.x = smem[(j * 4 + 0) * 68 + row];
      ov.y = smem[(j * 4 + 1) * 68 + row];
      ov.z = smem[(j * 4 + 2) * 68 + row];
      ov.w = smem[(j * 4 + 3) * 68 + row];
      *(float4*)(WfT + (size_t)(tc * 64 + row) * WFT_LD + tr * 64 + j * 4) = ov;
    }
    return;
  }

  const int mt = bx >> 2;
  const int nt = bx & 3;
  const int h0 = nt * 64;
  const bool isq = (mt < 16);

  const int srow = t >> 4;           // staging rows: srow + {0,16,32,48}
  const int sc4  = t & 15;
  const int lane = t & 63, w = t >> 6;
  const int m0w = (w >> 1) * 32, n0w = (w & 1) * 32;
  const int lr = lane & 15, lg = lane >> 4;

  const float* src;
  int coff, bb = 0, jb0 = 0, cntb = 0;
  int rowg[4];

  if (isq) {
    src  = q + (size_t)(mt * 64) * DIM;
    coff = 0;
#pragma unroll
    for (int p = 0; p < 4; ++p) rowg[p] = srow + p * 16;
  } else {
    const int ki = mt - 16;          // 0..127
    bb  = ki >> 3;                   // batch
    jb0 = (ki & 7) * 64;             // compacted window start
    // ---- inline mask scan: thread t handles entries 2t, 2t+1 ----
    const int e0 = (mask[bb * NI + 2 * t] == 0);
    const int e1 = (mask[bb * NI + 2 * t + 1] == 0);
    const int ps = e0 + e1;
    int x = ps;
#pragma unroll
    for (int off = 1; off < 64; off <<= 1) {
      int y = __shfl_up(x, off, 64);
      if (lane >= off) x += y;
    }
    if (lane == 63) swtot[w] = x;
    if (t < 64) idx_s[t] = 0;        // safe default for tail rows
    __syncthreads();
    int woffv = 0;
#pragma unroll
    for (int w2 = 0; w2 < 4; ++w2) {
      int v_ = swtot[w2];
      if (w2 < w) woffv += v_;
      cntb += v_;
    }
    const int excl = woffv + x - ps;          // prefix before entry 2t
    const int p0 = excl, p1 = excl + e0;
    if (e0 && p0 >= jb0 && p0 < jb0 + 64) idx_s[p0 - jb0] = 2 * t;
    if (e1 && p1 >= jb0 && p1 < jb0 + 64) idx_s[p1 - jb0] = 2 * t + 1;
    __syncthreads();
    if (jb0 >= cntb) return;         // block-uniform: nothing to do
    src  = k + (size_t)bb * NI * DIM;
    coff = DIM;
#pragma unroll
    for (int p = 0; p < 4; ++p) rowg[p] = idx_s[srow + p * 16];
  }

  f32x4 acc[2][2] = {};

  float4 aR[4], wR[4];
#define LOADC(c0_)                                                              \
  _Pragma("unroll")                                                             \
  for (int p = 0; p < 4; ++p) {                                                 \
    aR[p] = *(const float4*)(src + (size_t)rowg[p] * DIM + (c0_) + sc4 * 4);    \
    wR[p] = *(const float4*)(W1 + (size_t)(h0 + srow + p * 16) * (2 * DIM) + coff + (c0_) + sc4 * 4); \
  }

  LOADC(0)

  for (int c = 0; c < 4; ++c) {
    // ---- convert chunk c (in regs) to bf16 hi/lo and stage to LDS ----
#pragma unroll
    for (int p = 0; p < 4; ++p) {
      int row = srow + p * 16;
      int boff = row * 144 + sc4 * 8;     // byte offset within each array
      unsigned int h0_, h1_, h2_, h3_;
      float l0, l1, l2, l3;
      split2(aR[p].x, h0_, l0); split2(aR[p].y, h1_, l1);
      split2(aR[p].z, h2_, l2); split2(aR[p].w, h3_, l3);
      *(U2*)(smemRaw + OFF_AH + boff) = { h0_ | (h1_ << 16), h2_ | (h3_ << 16) };
      *(U2*)(smemRaw + OFF_AL + boff) = { rne16(l0) | (rne16(l1) << 16),
                                          rne16(l2) | (rne16(l3) << 16) };
      split2(wR[p].x, h0_, l0); split2(wR[p].y, h1_, l1);
      split2(wR[p].z, h2_, l2); split2(wR[p].w, h3_, l3);
      *(U2*)(smemRaw + OFF_WH + boff) = { h0_ | (h1_ << 16), h2_ | (h3_ << 16) };
      *(U2*)(smemRaw + OFF_WL + boff) = { rne16(l0) | (rne16(l1) << 16),
                                          rne16(l2) | (rne16(l3) << 16) };
    }
    __syncthreads();

    if (c < 3) { LOADC((c + 1) * 64) }   // issue-early: flies under the MFMAs

    // ---- MFMA over this 64-wide K chunk: 2 k-steps of 32 ----
#pragma unroll
    for (int kk = 0; kk < 2; ++kk) {
      const int kb = kk * 64 + lg * 16;  // byte offset of this lane's 8 bf16
      bf16x8 ah[2], al[2], bh[2], bl[2];
#pragma unroll
      for (int mi = 0; mi < 2; ++mi) {
        int row = m0w + mi * 16 + lr;
        ah[mi] = __builtin_bit_cast(bf16x8, *(const u32x4*)(smemRaw + OFF_AH + row * 144 + kb));
        al[mi] = __builtin_bit_cast(bf16x8, *(const u32x4*)(smemRaw + OFF_AL + row * 144 + kb));
      }
#pragma unroll
      for (int ni = 0; ni < 2; ++ni) {
        int row = n0w + ni * 16 + lr;
        bh[ni] = __builtin_bit_cast(bf16x8, *(const u32x4*)(smemRaw + OFF_WH + row * 144 + kb));
        bl[ni] = __builtin_bit_cast(bf16x8, *(const u32x4*)(smemRaw + OFF_WL + row * 144 + kb));
      }
#pragma unroll
      for (int mi = 0; mi < 2; ++mi)
#pragma unroll
        for (int ni = 0; ni < 2; ++ni) {
          acc[mi][ni] = __builtin_amdgcn_mfma_f32_16x16x32_bf16(ah[mi], bh[ni], acc[mi][ni], 0, 0, 0);
          acc[mi][ni] = __builtin_amdgcn_mfma_f32_16x16x32_bf16(ah[mi], bl[ni], acc[mi][ni], 0, 0, 0);
          acc[mi][ni] = __builtin_amdgcn_mfma_f32_16x16x32_bf16(al[mi], bh[ni], acc[mi][ni], 0, 0, 0);
        }
    }
    __syncthreads();
  }

  // ---- epilogue. C/D layout (m89-verified): col(n)=lane&15, row(m)=(lane>>4)*4+reg
  if (isq) {
    const int r0 = mt * 64;
#pragma unroll
    for (int ni = 0; ni < 2; ++ni) {
      int h = h0 + n0w + ni * 16 + lr;
      float b1v = b1[h];
#pragma unroll
      for (int mi = 0; mi < 2; ++mi)
#pragma unroll
        for (int rg = 0; rg < 4; ++rg) {
          int r = r0 + m0w + mi * 16 + lg * 4 + rg;
          Eq[(size_t)r * DIM + h] =
              __builtin_amdgcn_exp2f((acc[mi][ni][rg] + b1v) * CSCALE);
        }
    }
  } else {
    const int lim = cntb - jb0;      // valid local rows in this window
#pragma unroll
    for (int mi = 0; mi < 2; ++mi)
#pragma unroll
      for (int rg = 0; rg < 4; ++rg) {
        int local = m0w + mi * 16 + lg * 4 + rg;
        if (local < lim) {
          int pos = jb0 + local;     // dense compacted slot
#pragma unroll
          for (int ni = 0; ni < 2; ++ni) {
            int h = h0 + n0w + ni * 16 + lr;
            Ek4[((size_t)(bb * 64 + (h >> 2)) * NIP + pos) * 4 + (h & 3)] =
                __builtin_amdgcn_exp2f(acc[mi][ni][rg] * CSCALE);
          }
        }
      }
  }
}

__device__ __forceinline__ void f4arr(float4 v, float* a) {
  a[0] = v.x; a[1] = v.y; a[2] = v.z; a[3] = v.w;
}

// ---------------------------------------------------------------------------
// Kernel 2: one block (512 threads) per (b, o-pair). Grid 512. XCD-swizzled.
// DEEP-PREFETCH variant: phases 1/3/4 batch 16/8/16 loads into register
// arrays before consuming (raise per-wave memory-level parallelism from ~2
// to 8-16 in-flight). Eq/W2 staged in LDS so the only vmem stream in the
// hot loops is the prefetched one. Arithmetic order per output unchanged.
// ---------------------------------------------------------------------------
__global__ __launch_bounds__(512, 4) void attn_kernel(
    const float* __restrict__ Eq, const float* __restrict__ Ek4,
    const float* __restrict__ v, const int* __restrict__ mask,
    const float* __restrict__ W2, const float* __restrict__ b2,
    const float* __restrict__ WfT, const float* __restrict__ bf,
    float* __restrict__ out, float* __restrict__ attn_out)
{
  __shared__ float sc[OT][NI];        // 4 KB (compacted attn weights)
  __shared__ int   idxs[NI];          // 2 KB
  __shared__ float qs[OT][DIM];       // 2 KB
  __shared__ float w2s[DIM];          // 1 KB
  __shared__ float pvp[8][OT][DIM];   // 16 KB
  __shared__ float o0[OT][DIM];       // 2 KB
  __shared__ float red4[8][OT];
  __shared__ float redw[8];
  __shared__ int   swtot8[8];

  const int t    = threadIdx.x;
  const int lane = t & 63;
  const int wid  = t >> 6;

  const int blk  = blockIdx.x;
  const int tile = (blk & 7) * 64 + (blk >> 3);   // XCD swizzle
  const int b    = tile >> 5;
  const int bo0  = b * 64 + (tile & 31) * OT;

  // ---- inline mask scan ----
  const int unm = (mask[b * NI + t] == 0) ? 1 : 0;
  unsigned long long bal = __ballot(unm);
  int my = __popcll(bal & ((1ull << lane) - 1ull));
  if (lane == 0) swtot8[wid] = __popcll(bal);

  // ---- stage Eq rows + W2 into LDS (disjoint thread groups) ----
  if (t < 128) {
    const int r = t >> 6, part = t & 63;
    *(float4*)&qs[r][part * 4] =
        *(const float4*)(Eq + (size_t)(bo0 + r) * DIM + part * 4);
  } else if (t < 192) {
    const int part = t - 128;
    *(float4*)&w2s[part * 4] = *(const float4*)(W2 + part * 4);
  }

  // ---- sumW2 ----
  float partial = (t < DIM) ? W2[t] : 0.f;
#pragma unroll
  for (int off = 32; off >= 1; off >>= 1) partial += __shfl_xor(partial, off, 64);
  if (lane == 0) redw[wid] = partial;
  __syncthreads();                               // B1

  int cntb = 0, woffv = 0;
#pragma unroll
  for (int w = 0; w < 8; ++w) {
    int v_ = swtot8[w];
    if (w < wid) woffv += v_;
    cntb += v_;
  }
  const int myPos = unm ? (woffv + my) : -1;
  if (unm) idxs[myPos] = t;          // read in phase 3, after barriers

  float sumw2 = 0.f;
#pragma unroll
  for (int w = 0; w < 8; ++w) sumw2 += redw[w];
  const float base = sumw2 + b2[0];

  // ---- phase 1: scores for compacted column j = t; 16-deep kq prefetch ----
  const int j = t;
  const bool active = (j < cntb);
  const int jc = active ? j : (cntb > 0 ? cntb - 1 : 0);   // clamped safe index
  const float4* kb4 = (const float4*)Ek4 + (size_t)b * 64 * NIP;  // [hq*NIP + j]

  float acc0 = 0.f, acc1 = 0.f;
  if (wid * 64 < cntb) {                 // wave-uniform skip of dead waves
    const float4* kp = kb4 + jc;
#pragma unroll
    for (int c0 = 0; c0 < 64; c0 += 16) {
      float4 kqr[16];
#pragma unroll
      for (int u = 0; u < 16; ++u)       // 16 independent loads in flight
        kqr[u] = kp[(size_t)(c0 + u) * NIP];
#pragma unroll
      for (int u = 0; u < 16; ++u) {
        const int hq = c0 + u;
        float wr[4], q0r[4], q1r[4], kv[4];
        f4arr(*(const float4*)&w2s[hq * 4], wr);       // LDS broadcast
        f4arr(*(const float4*)&qs[0][hq * 4], q0r);
        f4arr(*(const float4*)&qs[1][hq * 4], q1r);
        f4arr(kqr[u], kv);
#pragma unroll
        for (int pr = 0; pr < 2; ++pr) {               // pairs (0,1), (2,3)
          const int ea = pr * 2, eb = pr * 2 + 1;
          float A0 = fmaf(q0r[ea], kv[ea], 1.f);
          float B0 = fmaf(q0r[eb], kv[eb], 1.f);
          float N0 = fmaf(wr[eb], A0, wr[ea] * B0);
          acc0 = fmaf(N0, __builtin_amdgcn_rcpf(A0 * B0), acc0);
          float A1 = fmaf(q1r[ea], kv[ea], 1.f);
          float B1 = fmaf(q1r[eb], kv[eb], 1.f);
          float N1 = fmaf(wr[eb], A1, wr[ea] * B1);
          acc1 = fmaf(N1, __builtin_amdgcn_rcpf(A1 * B1), acc1);
        }
      }
    }
  }

  float s0 = active ? (base - 2.f * acc0) : -INFINITY;
  float s1 = active ? (base - 2.f * acc1) : -INFINITY;

  // ---- phase 2: softmax over compacted set, no max-subtraction ----
  float p0 = __builtin_amdgcn_exp2f(s0 * 1.4426950408889634f);
  float p1 = __builtin_amdgcn_exp2f(s1 * 1.4426950408889634f);
  float ps0 = p0, ps1 = p1;
#pragma unroll
  for (int off = 32; off >= 1; off >>= 1) {
    ps0 += __shfl_xor(ps0, off, 64);
    ps1 += __shfl_xor(ps1, off, 64);
  }
  __syncthreads();               // redw reads done; red4 safe
  if (lane == 0) { red4[wid][0] = ps0; red4[wid][1] = ps1; }
  __syncthreads();
  float ss0 = 0.f, ss1 = 0.f;
#pragma unroll
  for (int w = 0; w < 8; ++w) { ss0 += red4[w][0]; ss1 += red4[w][1]; }
  const float a0 = p0 * __builtin_amdgcn_rcpf(ss0);
  const float a1 = p1 * __builtin_amdgcn_rcpf(ss1);
  sc[0][j] = a0;                 // compacted slot (0 for inactive j)
  sc[1][j] = a1;
  __syncthreads();

  // attn_out scatter-back: original column i = t; masked -> exact 0
  {
    float w0 = (myPos >= 0) ? sc[0][myPos] : 0.f;
    float w1 = (myPos >= 0) ? sc[1][myPos] : 0.f;
    attn_out[(size_t)(bo0 + 0) * NI + t] = w0;
    attn_out[(size_t)(bo0 + 1) * NI + t] = w1;
  }

  // ---- phase 3: PV, 8-deep v-row prefetch. wave wid: j in [wid*64,+64) ----
  {
    const int d4 = lane;
    float4 av0 = {0.f, 0.f, 0.f, 0.f};
    float4 av1 = {0.f, 0.f, 0.f, 0.f};
    const float4* vb4 = (const float4*)(v + (size_t)b * NI * DIM);
    const int jstart = wid * 64;
    const int jend = min(jstart + 64, cntb);
    int jb = jstart;
    for (; jb + 8 <= jend; jb += 8) {
      float4 vr[8];
      float sa0[8], sa1[8];
#pragma unroll
      for (int u = 0; u < 8; ++u) {
        int row = idxs[jb + u];                  // LDS (fast)
        vr[u] = vb4[(size_t)row * 64 + d4];      // 8 loads in flight
        sa0[u] = sc[0][jb + u];
        sa1[u] = sc[1][jb + u];
      }
#pragma unroll
      for (int u = 0; u < 8; ++u) {
        av0.x = fmaf(sa0[u], vr[u].x, av0.x);
        av0.y = fmaf(sa0[u], vr[u].y, av0.y);
        av0.z = fmaf(sa0[u], vr[u].z, av0.z);
        av0.w = fmaf(sa0[u], vr[u].w, av0.w);
        av1.x = fmaf(sa1[u], vr[u].x, av1.x);
        av1.y = fmaf(sa1[u], vr[u].y, av1.y);
        av1.z = fmaf(sa1[u], vr[u].z, av1.z);
        av1.w = fmaf(sa1[u], vr[u].w, av1.w);
      }
    }
    for (; jb < jend; ++jb) {                    // tail
      int row = idxs[jb];
      float sa0 = sc[0][jb], sa1 = sc[1][jb];
      float4 vv = vb4[(size_t)row * 64 + d4];
      av0.x = fmaf(sa0, vv.x, av0.x);
      av0.y = fmaf(sa0, vv.y, av0.y);
      av0.z = fmaf(sa0, vv.z, av0.z);
      av0.w = fmaf(sa0, vv.w, av0.w);
      av1.x = fmaf(sa1, vv.x, av1.x);
      av1.y = fmaf(sa1, vv.y, av1.y);
      av1.z = fmaf(sa1, vv.z, av1.z);
      av1.w = fmaf(sa1, vv.w, av1.w);
    }
    *(float4*)&pvp[wid][0][d4 * 4] = av0;        // dead waves store zeros
    *(float4*)&pvp[wid][1][d4 * 4] = av1;
  }
  __syncthreads();
  {
    int oo = t >> 8, d = t & 255;
    float sacc = 0.f;
#pragma unroll
    for (int w = 0; w < 8; ++w) sacc += pvp[w][oo][d];
    o0[oo][d] = sacc;
  }
  __syncthreads();

  // ---- phase 4: t<256 computes BOTH o's; 16-deep WfT prefetch ----
  if (t < DIM) {
    const int d = t;
    float f0 = 0.f, f1 = 0.f;
#pragma unroll
    for (int c0 = 0; c0 < 256; c0 += 16) {
      float wv[16];
#pragma unroll
      for (int u = 0; u < 16; ++u)               // 16 loads in flight
        wv[u] = WfT[(size_t)(c0 + u) * WFT_LD + d];
#pragma unroll
      for (int u = 0; u < 16; ++u) {
        f0 = fmaf(o0[0][c0 + u], wv[u], f0);
        f1 = fmaf(o0[1][c0 + u], wv[u], f1);
      }
    }
    float bfv = bf[d];
    f0 += bfv; f1 += bfv;
    f0 = (f0 >= 0.f) ? f0 : NEG_SLOPE * f0;
    f1 = (f1 >= 0.f) ? f1 : NEG_SLOPE * f1;
    out[(size_t)(bo0 + 0) * DIM + d] = f0;
    out[(size_t)(bo0 + 1) * DIM + d] = f1;
  }
}

// ---------------------------------------------------------------------------
extern "C" void kernel_launch(void* const* d_in, const int* in_sizes, int n_in,
                              void* d_out, int out_size, void* d_ws, size_t ws_size,
                              hipStream_t stream) {
  const float* q    = (const float*)d_in[0];
  const float* k    = (const float*)d_in[1];
  const float* v    = (const float*)d_in[2];
  const int*   mask = (const int*)d_in[3];
  const float* W1   = (const float*)d_in[4];
  const float* b1   = (const float*)d_in[5];
  const float* W2   = (const float*)d_in[6];
  const float* b2   = (const float*)d_in[7];
  const float* Wf   = (const float*)d_in[8];
  const float* bf   = (const float*)d_in[9];

  float* out      = (float*)d_out;                    // (16,64,256)
  float* attn_out = out + (size_t)BATCH * NO * DIM;   // (16,64,512)

  float* Eq   = (float*)d_ws;                         // 1024 x 256
  float* Ek4  = Eq + (size_t)BATCH * NO * DIM;        // 16 x 64 x NIP x 4
  float* WfT  = Ek4 + (size_t)BATCH * 64 * NIP * 4;   // 256 x WFT_LD

  proj_kernel<<<592, 256, 0, stream>>>(q, k, W1, b1, Wf, mask, Eq, Ek4, WfT);
  attn_kernel<<<(BATCH * NO) / OT, 512, 0, stream>>>(Eq, Ek4, v, mask,
                                                     W2, b2, WfT, bf, out, attn_out);
}